// Round 1
// baseline (4238.788 us; speedup 1.0000x reference)
//
#include <hip/hip_runtime.h>
#include <hip/hip_bf16.h>

#define BATCH 64
#define SEQ   2048
#define ISZ   256
#define H     256
#define G4    1024            // 4*H
#define M_TOT (BATCH*SEQ)     // 131072

typedef _Float16 half8  __attribute__((ext_vector_type(8)));
typedef _Float16 half2v __attribute__((ext_vector_type(2)));
typedef float    f32x4  __attribute__((ext_vector_type(4)));

union U32H2 { unsigned int u; half2v h; };
static __device__ __forceinline__ half2v u2h(unsigned int u){ U32H2 x; x.u = u; return x.h; }

#if __has_builtin(__builtin_amdgcn_fdot2)
#define FDOT2(w,hp,acc) __builtin_amdgcn_fdot2(u2h(w), u2h(hp), (acc), false)
#else
static __device__ __forceinline__ float fdot2_sw(unsigned int w, unsigned int hp, float acc){
  half2v wv = u2h(w), hv = u2h(hp);
  return acc + (float)wv[0]*(float)hv[0] + (float)wv[1]*(float)hv[1];
}
#define FDOT2(w,hp,acc) fdot2_sw((w),(hp),(acc))
#endif

// ---------------------------------------------------------------------------
// Prep: f16-convert W_ih, pack W_hh into k2-major f16 pairs, fuse biases.
// Wpk[k2*1024 + t] = (f16)W_hh[t][2k2] | (f16)W_hh[t][2k2+1] << 16
// ---------------------------------------------------------------------------
__global__ __launch_bounds__(256) void prep_kernel(
    const float* __restrict__ Wih, const float* __restrict__ Whh,
    const float* __restrict__ bih, const float* __restrict__ bhh,
    _Float16* __restrict__ Wihf, unsigned int* __restrict__ Wpk,
    float* __restrict__ bias) {
  const int idx = blockIdx.x * 256 + threadIdx.x;     // grid covers 262144 exactly
  Wihf[idx] = (_Float16)Wih[idx];
  if (idx < 131072) {
    const int t = idx & 1023, k2 = idx >> 10;
    U32H2 p;
    p.h[0] = (_Float16)Whh[t*256 + 2*k2];
    p.h[1] = (_Float16)Whh[t*256 + 2*k2 + 1];
    Wpk[idx] = p.u;
  }
  if (idx < 1024) bias[idx] = bih[idx] + bhh[idx];
}

// ---------------------------------------------------------------------------
// Phase 1: x_proj GEMM. C[m][n] = sum_k A[m][k]*B[n][k] + bias[n], f16 MFMA.
// A = x (fp32, converted during staging), B = Wihf (f16 [1024][256] row-major).
// 128x128 tile, BK=32, 256 threads (4 waves, each a 64x64 quadrant of 4x4
// 16x16x32 mfma). Single-buffered LDS, +8 f16 pad breaks bank conflicts.
// ---------------------------------------------------------------------------
#define BM 128
#define BN 128
#define BK 32
#define LDA 40

__global__ __launch_bounds__(256) void xproj_gemm(
    const float* __restrict__ X, const _Float16* __restrict__ Wihf,
    const float* __restrict__ bias, _Float16* __restrict__ XP) {
  __shared__ _Float16 As[BM*LDA];
  __shared__ _Float16 Bs[BN*LDA];
  const int tid  = threadIdx.x;
  const int m0   = blockIdx.x * BM;
  const int n0   = blockIdx.y * BN;
  const int lane = tid & 63;
  const int w    = tid >> 6;
  const int wm   = w & 1, wn = w >> 1;
  const int row  = tid >> 1, hlf = tid & 1;   // staging map: 2 threads/row

  f32x4 acc[4][4];
  #pragma unroll
  for (int mi = 0; mi < 4; ++mi)
    #pragma unroll
    for (int ni = 0; ni < 4; ++ni)
      acc[mi][ni] = (f32x4){0.f, 0.f, 0.f, 0.f};

  for (int kt = 0; kt < ISZ/BK; ++kt) {
    const int k0 = kt * BK;
    __syncthreads();
    // stage A (fp32 -> f16) : 16 floats per thread
    {
      const float4* pa = (const float4*)(X + (size_t)(m0+row)*ISZ + k0 + hlf*16);
      float4 f0 = pa[0], f1 = pa[1], f2 = pa[2], f3 = pa[3];
      half8 h0, h1;
      h0[0]=(_Float16)f0.x; h0[1]=(_Float16)f0.y; h0[2]=(_Float16)f0.z; h0[3]=(_Float16)f0.w;
      h0[4]=(_Float16)f1.x; h0[5]=(_Float16)f1.y; h0[6]=(_Float16)f1.z; h0[7]=(_Float16)f1.w;
      h1[0]=(_Float16)f2.x; h1[1]=(_Float16)f2.y; h1[2]=(_Float16)f2.z; h1[3]=(_Float16)f2.w;
      h1[4]=(_Float16)f3.x; h1[5]=(_Float16)f3.y; h1[6]=(_Float16)f3.z; h1[7]=(_Float16)f3.w;
      *(half8*)&As[row*LDA + hlf*16]     = h0;
      *(half8*)&As[row*LDA + hlf*16 + 8] = h1;
      // stage B (already f16): 16 halves per thread
      const half8* pb = (const half8*)(Wihf + (size_t)(n0+row)*ISZ + k0 + hlf*16);
      half8 b0 = pb[0], b1 = pb[1];
      *(half8*)&Bs[row*LDA + hlf*16]     = b0;
      *(half8*)&Bs[row*LDA + hlf*16 + 8] = b1;
    }
    __syncthreads();
    const int kch = (lane >> 4) * 8;
    const int rm  = wm*64 + (lane & 15);
    const int rn  = wn*64 + (lane & 15);
    half8 af[4], bf[4];
    #pragma unroll
    for (int i = 0; i < 4; ++i) {
      af[i] = *(const half8*)&As[(rm + i*16)*LDA + kch];
      bf[i] = *(const half8*)&Bs[(rn + i*16)*LDA + kch];
    }
    #pragma unroll
    for (int mi = 0; mi < 4; ++mi)
      #pragma unroll
      for (int ni = 0; ni < 4; ++ni)
        acc[mi][ni] = __builtin_amdgcn_mfma_f32_16x16x32_f16(af[mi], bf[ni], acc[mi][ni], 0, 0, 0);
  }
  // epilogue: C/D layout col=lane&15, row=(lane>>4)*4+r
  const int col = lane & 15, qr = (lane >> 4) * 4;
  #pragma unroll
  for (int ni = 0; ni < 4; ++ni) {
    const int n  = n0 + wn*64 + ni*16 + col;
    const float bs = bias[n];
    #pragma unroll
    for (int mi = 0; mi < 4; ++mi) {
      #pragma unroll
      for (int r = 0; r < 4; ++r) {
        const int m = m0 + wm*64 + mi*16 + qr + r;
        XP[(size_t)m*G4 + n] = (_Float16)(acc[mi][ni][r] + bs);
      }
    }
  }
}

// ---------------------------------------------------------------------------
// Phase 2: persistent per-batch-item scan. 64 WGs x 1024 threads, thread t
// owns gate row t. W_hh resident: 100 f16-pairs in VGPRs + 28 pairs in LDS
// (112 KB, [quad][tid] uint4 layout = bank-optimal). h kept as packed f16
// pairs in LDS (broadcast reads). Gates exchanged through LDS; threads 0..255
// own (c,h) for h-element j. 2 barriers/step.
// ---------------------------------------------------------------------------
#define NR  100   // register-resident pairs (k2 = 0..99)
#define NLQ 7     // LDS-resident pair-quads (k2 = 100..127)

__global__ __launch_bounds__(1024) void lstm_scan(
    const _Float16* __restrict__ XP, const unsigned int* __restrict__ Wpk,
    float* __restrict__ out) {
  __shared__ uint4 wlds[NLQ*1024];        // 114688 B
  __shared__ float act[G4];               // 4096 B
  __shared__ unsigned int h2[H/2];        // 512 B: h as packed f16 pairs
  const int t = threadIdx.x;
  const int b = blockIdx.x;

  unsigned int wreg[NR];
  #pragma unroll
  for (int i = 0; i < NR; ++i) wreg[i] = Wpk[i*1024 + t];
  #pragma unroll
  for (int q = 0; q < NLQ; ++q) {
    uint4 v;
    v.x = Wpk[(NR + 4*q + 0)*1024 + t];
    v.y = Wpk[(NR + 4*q + 1)*1024 + t];
    v.z = Wpk[(NR + 4*q + 2)*1024 + t];
    v.w = Wpk[(NR + 4*q + 3)*1024 + t];
    wlds[q*1024 + t] = v;
  }
  if (t < H/2) h2[t] = 0u;
  float c = 0.f;
  const _Float16* xb = XP + (size_t)b*SEQ*G4 + t;
  float xcur = (float)xb[0];
  float* outb = out + (size_t)b*SEQ*H;
  __syncthreads();

  #pragma unroll 1
  for (int s = 0; s < SEQ; ++s) {
    const int sn = (s + 1 < SEQ) ? (s + 1) : s;
    const _Float16 xnext = xb[(size_t)sn * G4];   // prefetch, used next iter

    float acc0 = xcur, acc1 = 0.f;
    #pragma unroll
    for (int q = 0; q < NR/4; ++q) {              // k2 = 0..99 (registers)
      uint4 hq = *(const uint4*)(h2 + 4*q);
      acc0 = FDOT2(wreg[4*q+0], hq.x, acc0);
      acc1 = FDOT2(wreg[4*q+1], hq.y, acc1);
      acc0 = FDOT2(wreg[4*q+2], hq.z, acc0);
      acc1 = FDOT2(wreg[4*q+3], hq.w, acc1);
    }
    #pragma unroll
    for (int q = 0; q < NLQ; ++q) {               // k2 = 100..127 (LDS)
      uint4 hq = *(const uint4*)(h2 + NR + 4*q);
      uint4 wv = wlds[q*1024 + t];
      acc0 = FDOT2(wv.x, hq.x, acc0);
      acc1 = FDOT2(wv.y, hq.y, acc1);
      acc0 = FDOT2(wv.z, hq.z, acc0);
      acc1 = FDOT2(wv.w, hq.w, acc1);
    }
    const float gate = acc0 + acc1;
    // rows 0-255=i(sig), 256-511=f(sig), 512-767=g(tanh), 768-1023=o(sig);
    // branch is wave-uniform.
    float a;
    if (t < 512 || t >= 768) a = 1.f / (1.f + __expf(-gate));
    else                     a = 2.f / (1.f + __expf(-2.f*gate)) - 1.f;
    act[t] = a;
    __syncthreads();
    if (t < H) {
      const float gi = act[t], gf = act[H+t], gg = act[2*H+t], go = act[3*H+t];
      c = gf*c + gi*gg;
      const float th = 2.f / (1.f + __expf(-2.f*c)) - 1.f;
      const float h = go*th;
      outb[(size_t)s*H + t] = h;
      ((_Float16*)h2)[t] = (_Float16)h;
      if (s == SEQ-1) {
        out[(size_t)BATCH*SEQ*H + (size_t)b*H + t] = h;                 // final h
        out[(size_t)BATCH*SEQ*H + (size_t)BATCH*H + (size_t)b*H + t] = c; // final c
      }
    }
    xcur = (float)xnext;
    __syncthreads();
  }
}

// ---------------------------------------------------------------------------
// ws layout: [ XP f16 256MB | Wihf f16 512KB | Wpk u32 512KB | bias f32 4KB ]
// ---------------------------------------------------------------------------
extern "C" void kernel_launch(void* const* d_in, const int* in_sizes, int n_in,
                              void* d_out, int out_size, void* d_ws, size_t ws_size,
                              hipStream_t stream) {
  const float* x   = (const float*)d_in[0];
  const float* Wih = (const float*)d_in[1];
  const float* Whh = (const float*)d_in[2];
  const float* bih = (const float*)d_in[3];
  const float* bhh = (const float*)d_in[4];
  float* out = (float*)d_out;

  char* ws = (char*)d_ws;
  const size_t XP_BYTES = (size_t)M_TOT * G4 * sizeof(_Float16);   // 268435456
  _Float16*     XPp  = (_Float16*)ws;
  _Float16*     Wihf = (_Float16*)(ws + XP_BYTES);
  unsigned int* Wpk  = (unsigned int*)(ws + XP_BYTES + 524288);
  float*        bias = (float*)(ws + XP_BYTES + 1048576);

  prep_kernel<<<dim3(1024),            dim3(256),  0, stream>>>(Wih, Whh, bih, bhh, Wihf, Wpk, bias);
  xproj_gemm <<<dim3(M_TOT/BM, G4/BN), dim3(256),  0, stream>>>(x, Wihf, bias, XPp);
  lstm_scan  <<<dim3(BATCH),           dim3(1024), 0, stream>>>(XPp, Wpk, out);
}